// Round 6
// baseline (199.765 us; speedup 1.0000x reference)
//
#include <hip/hip_runtime.h>

typedef unsigned short u16;
typedef unsigned int u32;
typedef __attribute__((ext_vector_type(8))) __bf16 bf16x8;
typedef __attribute__((ext_vector_type(4))) float f32x4;
typedef __attribute__((ext_vector_type(8))) unsigned short u16x8;
typedef __attribute__((ext_vector_type(4))) unsigned short u16x4;
typedef __attribute__((ext_vector_type(2))) unsigned int u32x2;
typedef __attribute__((ext_vector_type(4))) unsigned int u32x4;

#if defined(__has_builtin)
#if __has_builtin(__builtin_amdgcn_permlane32_swap) && __has_builtin(__builtin_amdgcn_permlane16_swap)
#define USE_PERMLANE 1
#endif
#endif
#ifndef USE_PERMLANE
#define USE_PERMLANE 0
#endif

__device__ __forceinline__ u16 f2bf(float f) {
    u32 u = __builtin_bit_cast(u32, f);
    u += 0x7fffu + ((u >> 16) & 1u);   // round-to-nearest-even
    return (u16)(u >> 16);
}

__device__ __forceinline__ float fexp2(float x) {
#if __has_builtin(__builtin_amdgcn_exp2f)
    return __builtin_amdgcn_exp2f(x);
#else
    return exp2f(x);
#endif
}

__device__ __forceinline__ float frcp(float x) {
#if __has_builtin(__builtin_amdgcn_rcpf)
    return __builtin_amdgcn_rcpf(x);
#else
    return 1.0f / x;
#endif
}

// ---------------- conversions ----------------
__global__ __launch_bounds__(256) void conv_h_kernel(const float* __restrict__ h,
                                                     u16* __restrict__ hb) {
    int i = blockIdx.x * 256 + threadIdx.x;
    float4 v = ((const float4*)h)[i];
    u16x4 o = { f2bf(v.x), f2bf(v.y), f2bf(v.z), f2bf(v.w) };
    ((u16x4*)hb)[i] = o;
}

// W [R][C] f32 -> Wt [C][R] bf16 (transpose + convert); rows < scale_rows get *scale
__global__ __launch_bounds__(256) void conv_wt_kernel(const float* __restrict__ W,
                                                      u16* __restrict__ Wt,
                                                      int R, int C,
                                                      int scale_rows, float scale) {
    __shared__ float tile[32][33];
    int t = threadIdx.x;
    int r = t >> 3, c4 = (t & 7) * 4;
    int gx = blockIdx.x * 32, gy = blockIdx.y * 32;
    float4 v = *(const float4*)&W[(size_t)(gy + r) * C + gx + c4];
    tile[r][c4 + 0] = v.x; tile[r][c4 + 1] = v.y;
    tile[r][c4 + 2] = v.z; tile[r][c4 + 3] = v.w;
    __syncthreads();
    float sc = (gx + r < scale_rows) ? scale : 1.0f;
    u16x4 o = { f2bf(tile[c4 + 0][r] * sc), f2bf(tile[c4 + 1][r] * sc),
                f2bf(tile[c4 + 2][r] * sc), f2bf(tile[c4 + 3][r] * sc) };
    *(u16x4*)&Wt[(size_t)(gx + r) * R + gy + c4] = o;
}

// ---------------- GEMM: C[M][N] = A[M][K] (bf16) x Bt[N][K]^T (bf16) ----------------
// reg-staged 2-phase (r2 structure)
template <int MODE>
__global__ __launch_bounds__(256) void gemm_bt_kernel(
        const u16* __restrict__ A, const u16* __restrict__ Bt,
        u16* __restrict__ Cb, const float* __restrict__ H, float* __restrict__ X,
        int M, int N, int K) {
    constexpr int LDT = 40;                 // 32 + 8 pad
    __shared__ u16 alds[2][128 * LDT];
    __shared__ u16 blds[2][128 * LDT];
    const int t = threadIdx.x;
    const int lane = t & 63;
    const int wave = t >> 6;
    const int wm = wave >> 1, wn = wave & 1;
    const int m0 = blockIdx.x * 128;
    const int n0 = blockIdx.y * 128;
    const int nk = K >> 5;

    const int srow = t >> 1;
    const int sch = (t & 1) * 2;
    const u16* ga = A + (size_t)(m0 + srow) * K + sch * 8;
    const u16* gb = Bt + (size_t)(n0 + srow) * K + sch * 8;
    const int wo = srow * LDT + sch * 8;

    u16x8 ra0 = *(const u16x8*)(ga);
    u16x8 ra1 = *(const u16x8*)(ga + 8);
    u16x8 rb0 = *(const u16x8*)(gb);
    u16x8 rb1 = *(const u16x8*)(gb + 8);
    *(u16x8*)&alds[0][wo] = ra0;  *(u16x8*)&alds[0][wo + 8] = ra1;
    *(u16x8*)&blds[0][wo] = rb0;  *(u16x8*)&blds[0][wo + 8] = rb1;

    f32x4 acc[4][4] = {};
    const int ko = (lane >> 4) * 8;
    const int arow_base = wm * 64 + (lane & 15);
    const int brow_base = wn * 64 + (lane & 15);

    int cur = 0;
    for (int kt = 0; kt < nk; ++kt) {
        __syncthreads();
        if (kt + 1 < nk) {
            const u16* gan = ga + (kt + 1) * 32;
            const u16* gbn = gb + (kt + 1) * 32;
            ra0 = *(const u16x8*)(gan);
            ra1 = *(const u16x8*)(gan + 8);
            rb0 = *(const u16x8*)(gbn);
            rb1 = *(const u16x8*)(gbn + 8);
        }
        bf16x8 afrag[4], bfrag[4];
#pragma unroll
        for (int m = 0; m < 4; ++m)
            afrag[m] = *(const bf16x8*)&alds[cur][(arow_base + m * 16) * LDT + ko];
#pragma unroll
        for (int n = 0; n < 4; ++n)
            bfrag[n] = *(const bf16x8*)&blds[cur][(brow_base + n * 16) * LDT + ko];
#pragma unroll
        for (int m = 0; m < 4; ++m)
#pragma unroll
            for (int n = 0; n < 4; ++n)
                acc[m][n] = __builtin_amdgcn_mfma_f32_16x16x32_bf16(afrag[m], bfrag[n],
                                                                   acc[m][n], 0, 0, 0);
        if (kt + 1 < nk) {
            *(u16x8*)&alds[cur ^ 1][wo] = ra0;  *(u16x8*)&alds[cur ^ 1][wo + 8] = ra1;
            *(u16x8*)&blds[cur ^ 1][wo] = rb0;  *(u16x8*)&blds[cur ^ 1][wo + 8] = rb1;
        }
        cur ^= 1;
    }

#pragma unroll
    for (int m = 0; m < 4; ++m)
#pragma unroll
        for (int n = 0; n < 4; ++n)
#pragma unroll
            for (int r = 0; r < 4; ++r) {
                int row = m0 + wm * 64 + m * 16 + (lane >> 4) * 4 + r;
                int col = n0 + wn * 64 + n * 16 + (lane & 15);
                size_t idx = (size_t)row * N + col;
                if (MODE == 0) Cb[idx] = f2bf(acc[m][n][r]);
                else           X[idx] = acc[m][n][r] + H[idx];
            }
}

// ---------------- V transpose ----------------
__global__ __launch_bounds__(256) void transpose_v_kernel(const u16* __restrict__ qkvb,
                                                          u16* __restrict__ vt) {
    __shared__ u16 tl[64][72];
    const int t = threadIdx.x;
    const int p = blockIdx.y;
    const int nn = p >> 1, b = p & 1;
    const int s0 = blockIdx.x * 64;
    const int r = t >> 2;
    const int ch = (t & 3) * 2;
    const u16* g = qkvb + ((size_t)(s0 + r) * 2 + b) * 3072 + 2048 + nn * 64;
    *(u16x8*)&tl[r][ch * 8]     = *(const u16x8*)(g + ch * 8);
    *(u16x8*)&tl[r][ch * 8 + 8] = *(const u16x8*)(g + ch * 8 + 8);
    __syncthreads();
    const int dh = t >> 2;
    const int sc = (t & 3) * 2;
    u16* o = vt + ((size_t)p * 64 + dh) * 2048 + s0;
#pragma unroll
    for (int q = 0; q < 2; ++q) {
        int scq = sc + q;
        u16x8 v;
#pragma unroll
        for (int j = 0; j < 8; ++j) v[j] = tl[scq * 8 + j][dh];
        *(u16x8*)(o + scq * 8) = v;
    }
}

// ---------------- causal flash attention ----------------
// swapped QK^T (exp2 units), QBLK=64, reg P-exchange, NO LDS: K/V fragments
// loaded straight from global (L1 absorbs the 4-wave redundancy). No barriers.
__global__ __launch_bounds__(256) void attn_kernel(const u16* __restrict__ qkvb,
                                                   const u16* __restrict__ vt,
                                                   u16* __restrict__ attnb) {
#if !USE_PERMLANE
    constexpr int LKT = 72;
    __shared__ u16 plds[4][16 * LKT];
#endif
    const int t = threadIdx.x;
    const int lane = t & 63;
    const int w = t >> 6;
    const int bid = blockIdx.x;
    // balanced + heavy-first qt map: every CU's 4-block work sum is constant
    const int g = bid >> 5;               // 0..31
    const int sq = g & 7, jq = g >> 3;
    const int qt = (jq == 0) ? (31 - sq) : (jq == 1) ? (16 + sq)
                 : (jq == 2) ? (15 - sq) : sq;
    const int p = bid & 31;
    const int nn = p >> 1, b = p & 1;
    const int i0 = qt * 64;

    const int li = lane & 15;
    const int lg = lane >> 4;

    // Q fragments (B-operand rows i = i0 + w*16 + li)
    const int qrow = i0 + w * 16 + li;
    const u16* qg = qkvb + ((size_t)qrow * 2 + b) * 3072 + nn * 64 + lg * 8;
    bf16x8 qa0 = *(const bf16x8*)(qg);
    bf16x8 qa1 = *(const bf16x8*)(qg + 32);

    // per-lane fragment base pointers (u16 units; row strides: qkvb 6144, vt 2048)
    const u16* kfb = qkvb + 1024 + nn * 64 + lg * 8 + ((size_t)li * 2 + b) * 3072;
    const u16* vfb = vt + ((size_t)(p * 64 + li)) * 2048 + lg * 8;

    f32x4 o[4] = {};                      // O[row = lg*4+r][d = cf*16+li]
    float mrun = -3.0e38f;
    float lrun = 0.f;

    const int nt = qt + 1;
    for (int jt = 0; jt < nt; ++jt) {
        const size_t j0 = (size_t)jt * 64;

        // K fragments straight from global: row j = j0+cf*16+li, cols lg*8(+32)
        bf16x8 kb[4][2];
#pragma unroll
        for (int cf = 0; cf < 4; ++cf) {
            const u16* kp = kfb + (j0 + cf * 16) * 6144;
            kb[cf][0] = *(const bf16x8*)(kp);
            kb[cf][1] = *(const bf16x8*)(kp + 32);
        }

        // swapped QK^T: st[cf][r] = S^T[j = j0+cf*16+lg*4+r][i = i0+w*16+li]
        f32x4 st[4];
        __builtin_amdgcn_s_setprio(1);
#pragma unroll
        for (int cf = 0; cf < 4; ++cf) {
            f32x4 z = {};
            z = __builtin_amdgcn_mfma_f32_16x16x32_bf16(kb[cf][0], qa0, z, 0, 0, 0);
            z = __builtin_amdgcn_mfma_f32_16x16x32_bf16(kb[cf][1], qa1, z, 0, 0, 0);
            st[cf] = z;
        }
        __builtin_amdgcn_s_setprio(0);

        // V fragments issued now (independent of softmax -> latency hidden under it)
        bf16x8 vbf[2][4];
#pragma unroll
        for (int ks = 0; ks < 2; ++ks)
#pragma unroll
            for (int cf = 0; cf < 4; ++cf)
                vbf[ks][cf] = *(const bf16x8*)(vfb + (size_t)cf * 32768 + j0 + ks * 32);

        if (jt == qt) {                   // mask only the diagonal tile
            const int it = w * 16 + li;
#pragma unroll
            for (int cf = 0; cf < 4; ++cf)
#pragma unroll
                for (int r = 0; r < 4; ++r) {
                    int jl = cf * 16 + lg * 4 + r;
                    if (jl > it) st[cf][r] = -3.0e38f;
                }
        }

        // row max: 15 in-reg + 2 shuffles
        float mloc = st[0][0];
#pragma unroll
        for (int cf = 0; cf < 4; ++cf)
#pragma unroll
            for (int r = 0; r < 4; ++r) mloc = fmaxf(mloc, st[cf][r]);
        mloc = fmaxf(mloc, __shfl_xor(mloc, 16, 64));
        mloc = fmaxf(mloc, __shfl_xor(mloc, 32, 64));

        // defer-rescale (T13)
        if (__any(mloc > mrun + 8.0f)) {
            float mnew = fmaxf(mrun, mloc);
            float alpha = fexp2(mrun - mnew);
            lrun *= alpha;
            mrun = mnew;
#pragma unroll
            for (int r = 0; r < 4; ++r) {
                float ar = __shfl(alpha, lg * 4 + r, 64);
#pragma unroll
                for (int cf = 0; cf < 4; ++cf) o[cf][r] *= ar;
            }
        }

#if USE_PERMLANE
        // P = exp2(s - m); pack pairs into bf16 words wv[cf][rr]
        float rsum = 0.f;
        u32 wv[4][2];
#pragma unroll
        for (int cf = 0; cf < 4; ++cf)
#pragma unroll
            for (int rr = 0; rr < 2; ++rr) {
                float p0 = fexp2(st[cf][2 * rr] - mrun);
                float p1 = fexp2(st[cf][2 * rr + 1] - mrun);
                rsum += p0 + p1;
                u32 wres;
                asm("v_cvt_pk_bf16_f32 %0, %1, %2" : "=v"(wres) : "v"(p0), "v"(p1));
                wv[cf][rr] = wres;
            }
        rsum += __shfl_xor(rsum, 16, 64);
        rsum += __shfl_xor(rsum, 32, 64);
        lrun += rsum;

        // PV with in-register P redistribution (permlane butterfly)
        __builtin_amdgcn_s_setprio(1);
#pragma unroll
        for (int ks = 0; ks < 2; ++ks) {
            u32x2 sa = __builtin_amdgcn_permlane32_swap(wv[2 * ks][0], wv[2 * ks + 1][0], false, false);
            u32x2 fa = __builtin_amdgcn_permlane16_swap(sa[0], sa[1], false, false);
            u32x2 sb = __builtin_amdgcn_permlane32_swap(wv[2 * ks][1], wv[2 * ks + 1][1], false, false);
            u32x2 fb = __builtin_amdgcn_permlane16_swap(sb[0], sb[1], false, false);
            u32x4 fw = { fa[0], fb[0], fa[1], fb[1] };
            bf16x8 pa = __builtin_bit_cast(bf16x8, fw);
#pragma unroll
            for (int cf = 0; cf < 4; ++cf)
                o[cf] = __builtin_amdgcn_mfma_f32_16x16x32_bf16(pa, vbf[ks][cf], o[cf], 0, 0, 0);
        }
        __builtin_amdgcn_s_setprio(0);
#else
        float rsum = 0.f;
#pragma unroll
        for (int cf = 0; cf < 4; ++cf) {
            u16x4 pw;
#pragma unroll
            for (int r = 0; r < 4; ++r) {
                float pv = fexp2(st[cf][r] - mrun);
                rsum += pv;
                pw[r] = f2bf(pv);
            }
            *(u16x4*)&plds[w][li * LKT + cf * 16 + lg * 4] = pw;
        }
        rsum += __shfl_xor(rsum, 16, 64);
        rsum += __shfl_xor(rsum, 32, 64);
        lrun += rsum;

        asm volatile("s_waitcnt lgkmcnt(0)" ::: "memory");
        __builtin_amdgcn_sched_barrier(0);

#pragma unroll
        for (int ks = 0; ks < 2; ++ks) {
            bf16x8 pa = *(const bf16x8*)&plds[w][li * LKT + ks * 32 + lg * 8];
#pragma unroll
            for (int cf = 0; cf < 4; ++cf)
                o[cf] = __builtin_amdgcn_mfma_f32_16x16x32_bf16(pa, vbf[ks][cf], o[cf], 0, 0, 0);
        }
#endif
    }

    float rinv = frcp(lrun);
#pragma unroll
    for (int r = 0; r < 4; ++r) {
        float rv = __shfl(rinv, lg * 4 + r, 64);
        int srowg = i0 + w * 16 + lg * 4 + r;
        u16* og = attnb + ((size_t)srowg * 2 + b) * 1024 + nn * 64;
#pragma unroll
        for (int cf = 0; cf < 4; ++cf)
            og[cf * 16 + li] = f2bf(o[cf][r] * rv);
    }
}

// ---------------- residual LayerNorm ----------------
__global__ __launch_bounds__(256) void ln_kernel(const float* __restrict__ X,
                                                 const float* __restrict__ gamma,
                                                 const float* __restrict__ beta,
                                                 float* __restrict__ out) {
    __shared__ float red[8];
    const int t = threadIdx.x;
    const int row = blockIdx.x;
    float4 v = ((const float4*)(X + (size_t)row * 1024))[t];
    float s = v.x + v.y + v.z + v.w;
#pragma unroll
    for (int off = 1; off < 64; off <<= 1) s += __shfl_xor(s, off, 64);
    if ((t & 63) == 0) red[t >> 6] = s;
    __syncthreads();
    float mu = (red[0] + red[1] + red[2] + red[3]) * (1.f / 1024.f);
    float dx = v.x - mu, dy = v.y - mu, dz = v.z - mu, dw = v.w - mu;
    float q = dx * dx + dy * dy + dz * dz + dw * dw;
#pragma unroll
    for (int off = 1; off < 64; off <<= 1) q += __shfl_xor(q, off, 64);
    if ((t & 63) == 0) red[4 + (t >> 6)] = q;
    __syncthreads();
    float var = (red[4] + red[5] + red[6] + red[7]) * (1.f / 1024.f);
    float rs = rsqrtf(var + 1e-5f);
    float4 g = ((const float4*)gamma)[t];
    float4 bt = ((const float4*)beta)[t];
    float4 o;
    o.x = dx * rs * g.x + bt.x;
    o.y = dy * rs * g.y + bt.y;
    o.z = dz * rs * g.z + bt.z;
    o.w = dw * rs * g.w + bt.w;
    ((float4*)(out + (size_t)row * 1024))[t] = o;
}

// ---------------- launch ----------------
extern "C" void kernel_launch(void* const* d_in, const int* in_sizes, int n_in,
                              void* d_out, int out_size, void* d_ws, size_t ws_size,
                              hipStream_t stream) {
    const float* h     = (const float*)d_in[0];
    // d_in[1] = attn_mask (deterministic causal triu; applied analytically)
    const float* Wqkv  = (const float*)d_in[2];
    const float* Wo    = (const float*)d_in[3];
    const float* gamma = (const float*)d_in[4];
    const float* beta  = (const float*)d_in[5];
    float* out = (float*)d_out;

    char* ws = (char*)d_ws;
    u16*   hb    = (u16*)(ws);
    u16*   wqkvt = (u16*)(ws + 8388608);
    u16*   wot   = (u16*)(ws + 14680064);
    u16*   qkvb  = (u16*)(ws + 16777216);
    u16*   vt    = (u16*)(ws + 41943040);
    u16*   attnb = (u16*)(ws + 50331648);
    float* xbuf  = (float*)(ws + 58720256);

    const float qscale = 0.125f * 1.44269504088896f;  // 1/sqrt(Dh) * log2(e)

    conv_h_kernel<<<4096, 256, 0, stream>>>(h, hb);
    conv_wt_kernel<<<dim3(96, 32), 256, 0, stream>>>(Wqkv, wqkvt, 1024, 3072, 1024, qscale);
    conv_wt_kernel<<<dim3(32, 32), 256, 0, stream>>>(Wo, wot, 1024, 1024, 0, 1.0f);
    gemm_bt_kernel<0><<<dim3(32, 24), 256, 0, stream>>>(hb, wqkvt, qkvb, nullptr, nullptr,
                                                        4096, 3072, 1024);
    transpose_v_kernel<<<dim3(32, 32), 256, 0, stream>>>(qkvb, vt);
    attn_kernel<<<1024, 256, 0, stream>>>(qkvb, vt, attnb);
    gemm_bt_kernel<1><<<dim3(32, 8), 256, 0, stream>>>(attnb, wot, nullptr, h, xbuf,
                                                       4096, 1024, 1024);
    ln_kernel<<<4096, 256, 0, stream>>>(xbuf, gamma, beta, out);
}

// Round 7
// 121.873 us; speedup vs baseline: 1.6391x; 1.6391x over previous
//
#include <hip/hip_runtime.h>

typedef unsigned short u16;
typedef unsigned int u32;
typedef __attribute__((ext_vector_type(8))) __bf16 bf16x8;
typedef __attribute__((ext_vector_type(4))) float f32x4;
typedef __attribute__((ext_vector_type(8))) unsigned short u16x8;
typedef __attribute__((ext_vector_type(4))) unsigned short u16x4;
typedef __attribute__((ext_vector_type(2))) unsigned int u32x2;
typedef __attribute__((ext_vector_type(4))) unsigned int u32x4;

#if defined(__has_builtin)
#if __has_builtin(__builtin_amdgcn_permlane32_swap) && __has_builtin(__builtin_amdgcn_permlane16_swap)
#define USE_PERMLANE 1
#endif
#endif
#ifndef USE_PERMLANE
#define USE_PERMLANE 0
#endif

__device__ __forceinline__ u16 f2bf(float f) {
    u32 u = __builtin_bit_cast(u32, f);
    u += 0x7fffu + ((u >> 16) & 1u);   // round-to-nearest-even
    return (u16)(u >> 16);
}

__device__ __forceinline__ float fexp2(float x) {
#if __has_builtin(__builtin_amdgcn_exp2f)
    return __builtin_amdgcn_exp2f(x);
#else
    return exp2f(x);
#endif
}

__device__ __forceinline__ float frcp(float x) {
#if __has_builtin(__builtin_amdgcn_rcpf)
    return __builtin_amdgcn_rcpf(x);
#else
    return 1.0f / x;
#endif
}

// ---------------- conversions ----------------
__global__ __launch_bounds__(256) void conv_h_kernel(const float* __restrict__ h,
                                                     u16* __restrict__ hb) {
    int i = blockIdx.x * 256 + threadIdx.x;
    float4 v = ((const float4*)h)[i];
    u16x4 o = { f2bf(v.x), f2bf(v.y), f2bf(v.z), f2bf(v.w) };
    ((u16x4*)hb)[i] = o;
}

// W [R][C] f32 -> Wt [C][R] bf16 (transpose + convert); rows < scale_rows get *scale
__global__ __launch_bounds__(256) void conv_wt_kernel(const float* __restrict__ W,
                                                      u16* __restrict__ Wt,
                                                      int R, int C,
                                                      int scale_rows, float scale) {
    __shared__ float tile[32][33];
    int t = threadIdx.x;
    int r = t >> 3, c4 = (t & 7) * 4;
    int gx = blockIdx.x * 32, gy = blockIdx.y * 32;
    float4 v = *(const float4*)&W[(size_t)(gy + r) * C + gx + c4];
    tile[r][c4 + 0] = v.x; tile[r][c4 + 1] = v.y;
    tile[r][c4 + 2] = v.z; tile[r][c4 + 3] = v.w;
    __syncthreads();
    float sc = (gx + r < scale_rows) ? scale : 1.0f;
    u16x4 o = { f2bf(tile[c4 + 0][r] * sc), f2bf(tile[c4 + 1][r] * sc),
                f2bf(tile[c4 + 2][r] * sc), f2bf(tile[c4 + 3][r] * sc) };
    *(u16x4*)&Wt[(size_t)(gx + r) * R + gy + c4] = o;
}

// ---------------- GEMM: C[M][N] = A[M][K] (bf16) x Bt[N][K]^T (bf16) ----------------
// reg-staged 2-phase, k-chunked LDS layout [chunk 0..3][row 0..127][8] (no pad,
// uniform-bank reads, 32KB total -> 4 blocks/CU). XCD-swizzled flat grid.
template <int MODE>
__global__ __launch_bounds__(256) void gemm_bt_kernel(
        const u16* __restrict__ A, const u16* __restrict__ Bt,
        u16* __restrict__ Cb, const float* __restrict__ H, float* __restrict__ X,
        int M, int N, int K) {
    __shared__ u16 alds[2][4096];           // [chunk*1024 + row*8]
    __shared__ u16 blds[2][4096];
    const int t = threadIdx.x;
    const int lane = t & 63;
    const int wave = t >> 6;
    const int wm = wave >> 1, wn = wave & 1;
    const int li = lane & 15, lg = lane >> 4;

    // XCD-aware bijective swizzle of flat grid (nwg % 8 == 0)
    const int mt = M >> 7;
    const int nwg = mt * (N >> 7);
    const int lin = blockIdx.x;
    const int swzb = (lin & 7) * (nwg >> 3) + (lin >> 3);
    const int m0 = (swzb % mt) * 128;
    const int n0 = (swzb / mt) * 128;
    const int nk = K >> 5;

    const int srow = t >> 1;                // 0..127
    const int sch = (t & 1) * 2;            // chunks {sch, sch+1}
    const u16* ga = A + (size_t)(m0 + srow) * K + sch * 8;
    const u16* gb = Bt + (size_t)(n0 + srow) * K + sch * 8;
    const int wo0 = sch * 1024 + srow * 8;
    const int wo1 = (sch + 1) * 1024 + srow * 8;

    u16x8 ra0 = *(const u16x8*)(ga);
    u16x8 ra1 = *(const u16x8*)(ga + 8);
    u16x8 rb0 = *(const u16x8*)(gb);
    u16x8 rb1 = *(const u16x8*)(gb + 8);
    *(u16x8*)&alds[0][wo0] = ra0;  *(u16x8*)&alds[0][wo1] = ra1;
    *(u16x8*)&blds[0][wo0] = rb0;  *(u16x8*)&blds[0][wo1] = rb1;

    f32x4 acc[4][4] = {};
    const int arow_base = wm * 64 + li;
    const int brow_base = wn * 64 + li;

    int cur = 0;
    for (int kt = 0; kt < nk; ++kt) {
        __syncthreads();
        if (kt + 1 < nk) {
            const u16* gan = ga + (kt + 1) * 32;
            const u16* gbn = gb + (kt + 1) * 32;
            ra0 = *(const u16x8*)(gan);
            ra1 = *(const u16x8*)(gan + 8);
            rb0 = *(const u16x8*)(gbn);
            rb1 = *(const u16x8*)(gbn + 8);
        }
        bf16x8 afrag[4], bfrag[4];
#pragma unroll
        for (int m = 0; m < 4; ++m)
            afrag[m] = *(const bf16x8*)&alds[cur][lg * 1024 + (arow_base + m * 16) * 8];
#pragma unroll
        for (int n = 0; n < 4; ++n)
            bfrag[n] = *(const bf16x8*)&blds[cur][lg * 1024 + (brow_base + n * 16) * 8];
#pragma unroll
        for (int m = 0; m < 4; ++m)
#pragma unroll
            for (int n = 0; n < 4; ++n)
                acc[m][n] = __builtin_amdgcn_mfma_f32_16x16x32_bf16(afrag[m], bfrag[n],
                                                                   acc[m][n], 0, 0, 0);
        if (kt + 1 < nk) {
            *(u16x8*)&alds[cur ^ 1][wo0] = ra0;  *(u16x8*)&alds[cur ^ 1][wo1] = ra1;
            *(u16x8*)&blds[cur ^ 1][wo0] = rb0;  *(u16x8*)&blds[cur ^ 1][wo1] = rb1;
        }
        cur ^= 1;
    }

#pragma unroll
    for (int m = 0; m < 4; ++m)
#pragma unroll
        for (int n = 0; n < 4; ++n)
#pragma unroll
            for (int r = 0; r < 4; ++r) {
                int row = m0 + wm * 64 + m * 16 + lg * 4 + r;
                int col = n0 + wn * 64 + n * 16 + li;
                size_t idx = (size_t)row * N + col;
                if (MODE == 0) Cb[idx] = f2bf(acc[m][n][r]);
                else           X[idx] = acc[m][n][r] + H[idx];
            }
}

// ---------------- V transpose ----------------
__global__ __launch_bounds__(256) void transpose_v_kernel(const u16* __restrict__ qkvb,
                                                          u16* __restrict__ vt) {
    __shared__ u16 tl[64][72];
    const int t = threadIdx.x;
    const int p = blockIdx.y;
    const int nn = p >> 1, b = p & 1;
    const int s0 = blockIdx.x * 64;
    const int r = t >> 2;
    const int ch = (t & 3) * 2;
    const u16* g = qkvb + ((size_t)(s0 + r) * 2 + b) * 3072 + 2048 + nn * 64;
    *(u16x8*)&tl[r][ch * 8]     = *(const u16x8*)(g + ch * 8);
    *(u16x8*)&tl[r][ch * 8 + 8] = *(const u16x8*)(g + ch * 8 + 8);
    __syncthreads();
    const int dh = t >> 2;
    const int sc = (t & 3) * 2;
    u16* o = vt + ((size_t)p * 64 + dh) * 2048 + s0;
#pragma unroll
    for (int q = 0; q < 2; ++q) {
        int scq = sc + q;
        u16x8 v;
#pragma unroll
        for (int j = 0; j < 8; ++j) v[j] = tl[scq * 8 + j][dh];
        *(u16x8*)(o + scq * 8) = v;
    }
}

// ---------------- causal flash attention ----------------
// r5 structure: swapped QK^T (exp2 units), QBLK=64, permlane P-exchange, K/V LDS
// double-buffer, single barrier/step, setprio. LDS now k-chunked [chunk][row][8]
// (no pad, 32KB, uniform-bank).
__global__ __launch_bounds__(256) void attn_kernel(const u16* __restrict__ qkvb,
                                                   const u16* __restrict__ vt,
                                                   u16* __restrict__ attnb) {
    __shared__ u16 klds[2][4096];          // [ (chunk 0..7)*512 + row*8 ]
    __shared__ u16 vlds[2][4096];
#if !USE_PERMLANE
    __shared__ u16 plds[4][16 * 72];
#endif
    const int t = threadIdx.x;
    const int lane = t & 63;
    const int w = t >> 6;
    const int bid = blockIdx.x;
    // balanced + heavy-first qt map: every CU's 4-block work sum is constant
    const int g = bid >> 5;               // 0..31
    const int sq = g & 7, jq = g >> 3;
    const int qt = (jq == 0) ? (31 - sq) : (jq == 1) ? (16 + sq)
                 : (jq == 2) ? (15 - sq) : sq;
    const int p = bid & 31;
    const int nn = p >> 1, b = p & 1;
    const int i0 = qt * 64;

    const int li = lane & 15;
    const int lg = lane >> 4;

    // Q fragments (B-operand rows i = i0 + w*16 + li)
    const int qrow = i0 + w * 16 + li;
    const u16* qg = qkvb + ((size_t)qrow * 2 + b) * 3072 + nn * 64 + lg * 8;
    bf16x8 qa0 = *(const bf16x8*)(qg);
    bf16x8 qa1 = *(const bf16x8*)(qg + 32);

    f32x4 o[4] = {};                      // O[row = lg*4+r][d = cf*16+li]
    float mrun = -3.0e38f;
    float lrun = 0.f;

    const int srow = t >> 2;              // 0..63
    const int sch = (t & 3) * 2;          // chunks {sch, sch+1}
    const u16* kg = qkvb + 1024 + nn * 64 + sch * 8;
    const u16* vg = vt + ((size_t)p * 64 + srow) * 2048 + sch * 8;
    const int w0 = sch * 512 + srow * 8;
    const int w1 = (sch + 1) * 512 + srow * 8;

    const int nt = qt + 1;
    u16x8 k0, k1, v0, v1;                 // issue-early staged regs (T14)
    {
        const u16* kgp = kg + ((size_t)srow * 2 + b) * 3072;
        k0 = *(const u16x8*)(kgp);  k1 = *(const u16x8*)(kgp + 8);
        v0 = *(const u16x8*)(vg);   v1 = *(const u16x8*)(vg + 8);
    }
    // prologue: tile 0 into buf0
    *(u16x8*)&klds[0][w0] = k0;  *(u16x8*)&klds[0][w1] = k1;
    *(u16x8*)&vlds[0][w0] = v0;  *(u16x8*)&vlds[0][w1] = v1;
    __syncthreads();

    for (int jt = 0; jt < nt; ++jt) {
        const int buf = jt & 1;
        if (jt + 1 < nt) {                // issue-early next-tile loads
            const u16* kgp = kg + ((size_t)(jt * 64 + 64 + srow) * 2 + b) * 3072;
            k0 = *(const u16x8*)(kgp);  k1 = *(const u16x8*)(kgp + 8);
            const u16* vgp = vg + jt * 64 + 64;
            v0 = *(const u16x8*)(vgp);  v1 = *(const u16x8*)(vgp + 8);
        }

        // swapped QK^T: st[cf][r] = S^T[j = jt*64+cf*16+lg*4+r][i = i0+w*16+li]
        f32x4 st[4];
        __builtin_amdgcn_s_setprio(1);
#pragma unroll
        for (int cf = 0; cf < 4; ++cf) {
            bf16x8 kb0 = *(const bf16x8*)&klds[buf][lg * 512 + (cf * 16 + li) * 8];
            bf16x8 kb1 = *(const bf16x8*)&klds[buf][(4 + lg) * 512 + (cf * 16 + li) * 8];
            f32x4 z = {};
            z = __builtin_amdgcn_mfma_f32_16x16x32_bf16(kb0, qa0, z, 0, 0, 0);
            z = __builtin_amdgcn_mfma_f32_16x16x32_bf16(kb1, qa1, z, 0, 0, 0);
            st[cf] = z;
        }
        __builtin_amdgcn_s_setprio(0);

        if (jt == qt) {                   // mask only the diagonal tile
            const int it = w * 16 + li;
#pragma unroll
            for (int cf = 0; cf < 4; ++cf)
#pragma unroll
                for (int r = 0; r < 4; ++r) {
                    int jl = cf * 16 + lg * 4 + r;
                    if (jl > it) st[cf][r] = -3.0e38f;
                }
        }

        // row max: 15 in-reg + 2 shuffles
        float mloc = st[0][0];
#pragma unroll
        for (int cf = 0; cf < 4; ++cf)
#pragma unroll
            for (int r = 0; r < 4; ++r) mloc = fmaxf(mloc, st[cf][r]);
        mloc = fmaxf(mloc, __shfl_xor(mloc, 16, 64));
        mloc = fmaxf(mloc, __shfl_xor(mloc, 32, 64));

        // defer-rescale (T13)
        if (__any(mloc > mrun + 8.0f)) {
            float mnew = fmaxf(mrun, mloc);
            float alpha = fexp2(mrun - mnew);
            lrun *= alpha;
            mrun = mnew;
#pragma unroll
            for (int r = 0; r < 4; ++r) {
                float ar = __shfl(alpha, lg * 4 + r, 64);
#pragma unroll
                for (int cf = 0; cf < 4; ++cf) o[cf][r] *= ar;
            }
        }

#if USE_PERMLANE
        // P = exp2(s - m); pack pairs into bf16 words wv[cf][rr]
        float rsum = 0.f;
        u32 wv[4][2];
#pragma unroll
        for (int cf = 0; cf < 4; ++cf)
#pragma unroll
            for (int rr = 0; rr < 2; ++rr) {
                float p0 = fexp2(st[cf][2 * rr] - mrun);
                float p1 = fexp2(st[cf][2 * rr + 1] - mrun);
                rsum += p0 + p1;
                u32 wres;
                asm("v_cvt_pk_bf16_f32 %0, %1, %2" : "=v"(wres) : "v"(p0), "v"(p1));
                wv[cf][rr] = wres;
            }
        rsum += __shfl_xor(rsum, 16, 64);
        rsum += __shfl_xor(rsum, 32, 64);
        lrun += rsum;

        // PV with in-register P redistribution (permlane butterfly)
        __builtin_amdgcn_s_setprio(1);
#pragma unroll
        for (int ks = 0; ks < 2; ++ks) {
            u32x2 sa = __builtin_amdgcn_permlane32_swap(wv[2 * ks][0], wv[2 * ks + 1][0], false, false);
            u32x2 fa = __builtin_amdgcn_permlane16_swap(sa[0], sa[1], false, false);
            u32x2 sb = __builtin_amdgcn_permlane32_swap(wv[2 * ks][1], wv[2 * ks + 1][1], false, false);
            u32x2 fb = __builtin_amdgcn_permlane16_swap(sb[0], sb[1], false, false);
            u32x4 fw = { fa[0], fb[0], fa[1], fb[1] };
            bf16x8 pa = __builtin_bit_cast(bf16x8, fw);
#pragma unroll
            for (int cf = 0; cf < 4; ++cf) {
                bf16x8 vb = *(const bf16x8*)&vlds[buf][(ks * 4 + lg) * 512 + (cf * 16 + li) * 8];
                o[cf] = __builtin_amdgcn_mfma_f32_16x16x32_bf16(pa, vb, o[cf], 0, 0, 0);
            }
        }
        __builtin_amdgcn_s_setprio(0);
#else
        float rsum = 0.f;
#pragma unroll
        for (int cf = 0; cf < 4; ++cf) {
            u16x4 pw;
#pragma unroll
            for (int r = 0; r < 4; ++r) {
                float pv = fexp2(st[cf][r] - mrun);
                rsum += pv;
                pw[r] = f2bf(pv);
            }
            *(u16x4*)&plds[w][li * 72 + cf * 16 + lg * 4] = pw;
        }
        rsum += __shfl_xor(rsum, 16, 64);
        rsum += __shfl_xor(rsum, 32, 64);
        lrun += rsum;

        asm volatile("s_waitcnt lgkmcnt(0)" ::: "memory");
        __builtin_amdgcn_sched_barrier(0);

#pragma unroll
        for (int ks = 0; ks < 2; ++ks) {
            bf16x8 pa = *(const bf16x8*)&plds[w][li * 72 + ks * 32 + lg * 8];
#pragma unroll
            for (int cf = 0; cf < 4; ++cf) {
                bf16x8 vb = *(const bf16x8*)&vlds[buf][(ks * 4 + lg) * 512 + (cf * 16 + li) * 8];
                o[cf] = __builtin_amdgcn_mfma_f32_16x16x32_bf16(pa, vb, o[cf], 0, 0, 0);
            }
        }
#endif

        // write-late: next tile into the other buffer (last read at jt-1, safe)
        if (jt + 1 < nt) {
            *(u16x8*)&klds[buf ^ 1][w0] = k0;  *(u16x8*)&klds[buf ^ 1][w1] = k1;
            *(u16x8*)&vlds[buf ^ 1][w0] = v0;  *(u16x8*)&vlds[buf ^ 1][w1] = v1;
        }
        __syncthreads();                  // single barrier per tile-step
    }

    float rinv = frcp(lrun);
#pragma unroll
    for (int r = 0; r < 4; ++r) {
        float rv = __shfl(rinv, lg * 4 + r, 64);
        int srowg = i0 + w * 16 + lg * 4 + r;
        u16* og = attnb + ((size_t)srowg * 2 + b) * 1024 + nn * 64;
#pragma unroll
        for (int cf = 0; cf < 4; ++cf)
            og[cf * 16 + li] = f2bf(o[cf][r] * rv);
    }
}

// ---------------- residual LayerNorm ----------------
__global__ __launch_bounds__(256) void ln_kernel(const float* __restrict__ X,
                                                 const float* __restrict__ gamma,
                                                 const float* __restrict__ beta,
                                                 float* __restrict__ out) {
    __shared__ float red[8];
    const int t = threadIdx.x;
    const int row = blockIdx.x;
    float4 v = ((const float4*)(X + (size_t)row * 1024))[t];
    float s = v.x + v.y + v.z + v.w;
#pragma unroll
    for (int off = 1; off < 64; off <<= 1) s += __shfl_xor(s, off, 64);
    if ((t & 63) == 0) red[t >> 6] = s;
    __syncthreads();
    float mu = (red[0] + red[1] + red[2] + red[3]) * (1.f / 1024.f);
    float dx = v.x - mu, dy = v.y - mu, dz = v.z - mu, dw = v.w - mu;
    float q = dx * dx + dy * dy + dz * dz + dw * dw;
#pragma unroll
    for (int off = 1; off < 64; off <<= 1) q += __shfl_xor(q, off, 64);
    if ((t & 63) == 0) red[4 + (t >> 6)] = q;
    __syncthreads();
    float var = (red[4] + red[5] + red[6] + red[7]) * (1.f / 1024.f);
    float rs = rsqrtf(var + 1e-5f);
    float4 g = ((const float4*)gamma)[t];
    float4 bt = ((const float4*)beta)[t];
    float4 o;
    o.x = dx * rs * g.x + bt.x;
    o.y = dy * rs * g.y + bt.y;
    o.z = dz * rs * g.z + bt.z;
    o.w = dw * rs * g.w + bt.w;
    ((float4*)(out + (size_t)row * 1024))[t] = o;
}

// ---------------- launch ----------------
extern "C" void kernel_launch(void* const* d_in, const int* in_sizes, int n_in,
                              void* d_out, int out_size, void* d_ws, size_t ws_size,
                              hipStream_t stream) {
    const float* h     = (const float*)d_in[0];
    // d_in[1] = attn_mask (deterministic causal triu; applied analytically)
    const float* Wqkv  = (const float*)d_in[2];
    const float* Wo    = (const float*)d_in[3];
    const float* gamma = (const float*)d_in[4];
    const float* beta  = (const float*)d_in[5];
    float* out = (float*)d_out;

    char* ws = (char*)d_ws;
    u16*   hb    = (u16*)(ws);
    u16*   wqkvt = (u16*)(ws + 8388608);
    u16*   wot   = (u16*)(ws + 14680064);
    u16*   qkvb  = (u16*)(ws + 16777216);
    u16*   vt    = (u16*)(ws + 41943040);
    u16*   attnb = (u16*)(ws + 50331648);
    float* xbuf  = (float*)(ws + 58720256);

    const float qscale = 0.125f * 1.44269504088896f;  // 1/sqrt(Dh) * log2(e)

    conv_h_kernel<<<4096, 256, 0, stream>>>(h, hb);
    conv_wt_kernel<<<dim3(96, 32), 256, 0, stream>>>(Wqkv, wqkvt, 1024, 3072, 1024, qscale);
    conv_wt_kernel<<<dim3(32, 32), 256, 0, stream>>>(Wo, wot, 1024, 1024, 0, 1.0f);
    gemm_bt_kernel<0><<<768, 256, 0, stream>>>(hb, wqkvt, qkvb, nullptr, nullptr,
                                               4096, 3072, 1024);
    transpose_v_kernel<<<dim3(32, 32), 256, 0, stream>>>(qkvb, vt);
    attn_kernel<<<1024, 256, 0, stream>>>(qkvb, vt, attnb);
    gemm_bt_kernel<1><<<256, 256, 0, stream>>>(attnb, wot, nullptr, h, xbuf,
                                               4096, 1024, 1024);
    ln_kernel<<<4096, 256, 0, stream>>>(xbuf, gamma, beta, out);
}

// Round 8
// 117.335 us; speedup vs baseline: 1.7025x; 1.0387x over previous
//
#include <hip/hip_runtime.h>

typedef unsigned short u16;
typedef unsigned int u32;
typedef __attribute__((ext_vector_type(8))) __bf16 bf16x8;
typedef __attribute__((ext_vector_type(4))) float f32x4;
typedef __attribute__((ext_vector_type(8))) unsigned short u16x8;
typedef __attribute__((ext_vector_type(4))) unsigned short u16x4;
typedef __attribute__((ext_vector_type(2))) unsigned int u32x2;
typedef __attribute__((ext_vector_type(4))) unsigned int u32x4;

#if defined(__has_builtin)
#if __has_builtin(__builtin_amdgcn_permlane32_swap) && __has_builtin(__builtin_amdgcn_permlane16_swap)
#define USE_PERMLANE 1
#endif
#endif
#ifndef USE_PERMLANE
#define USE_PERMLANE 0
#endif

__device__ __forceinline__ u16 f2bf(float f) {
    u32 u = __builtin_bit_cast(u32, f);
    u += 0x7fffu + ((u >> 16) & 1u);   // round-to-nearest-even
    return (u16)(u >> 16);
}

__device__ __forceinline__ float fexp2(float x) {
#if __has_builtin(__builtin_amdgcn_exp2f)
    return __builtin_amdgcn_exp2f(x);
#else
    return exp2f(x);
#endif
}

__device__ __forceinline__ float frcp(float x) {
#if __has_builtin(__builtin_amdgcn_rcpf)
    return __builtin_amdgcn_rcpf(x);
#else
    return 1.0f / x;
#endif
}

// ---------------- conversions ----------------
__global__ __launch_bounds__(256) void conv_h_kernel(const float* __restrict__ h,
                                                     u16* __restrict__ hb) {
    int i = blockIdx.x * 256 + threadIdx.x;
    float4 v = ((const float4*)h)[i];
    u16x4 o = { f2bf(v.x), f2bf(v.y), f2bf(v.z), f2bf(v.w) };
    ((u16x4*)hb)[i] = o;
}

// W [R][C] f32 -> Wt [C][R] bf16 (transpose + convert); rows < scale_rows get *scale
__global__ __launch_bounds__(256) void conv_wt_kernel(const float* __restrict__ W,
                                                      u16* __restrict__ Wt,
                                                      int R, int C,
                                                      int scale_rows, float scale) {
    __shared__ float tile[32][33];
    int t = threadIdx.x;
    int r = t >> 3, c4 = (t & 7) * 4;
    int gx = blockIdx.x * 32, gy = blockIdx.y * 32;
    float4 v = *(const float4*)&W[(size_t)(gy + r) * C + gx + c4];
    tile[r][c4 + 0] = v.x; tile[r][c4 + 1] = v.y;
    tile[r][c4 + 2] = v.z; tile[r][c4 + 3] = v.w;
    __syncthreads();
    float sc = (gx + r < scale_rows) ? scale : 1.0f;
    u16x4 o = { f2bf(tile[c4 + 0][r] * sc), f2bf(tile[c4 + 1][r] * sc),
                f2bf(tile[c4 + 2][r] * sc), f2bf(tile[c4 + 3][r] * sc) };
    *(u16x4*)&Wt[(size_t)(gx + r) * R + gy + c4] = o;
}

// ---------------- GEMM: C[M][N] = A[M][K] (bf16) x Bt[N][K]^T (bf16) ----------------
// reg-staged 2-phase, padded LDS (r5-proven structure)
template <int MODE>
__global__ __launch_bounds__(256) void gemm_bt_kernel(
        const u16* __restrict__ A, const u16* __restrict__ Bt,
        u16* __restrict__ Cb, const float* __restrict__ H, float* __restrict__ X,
        int M, int N, int K) {
    constexpr int LDT = 40;                 // 32 + 8 pad
    __shared__ u16 alds[2][128 * LDT];
    __shared__ u16 blds[2][128 * LDT];
    const int t = threadIdx.x;
    const int lane = t & 63;
    const int wave = t >> 6;
    const int wm = wave >> 1, wn = wave & 1;
    const int m0 = blockIdx.x * 128;
    const int n0 = blockIdx.y * 128;
    const int nk = K >> 5;

    const int srow = t >> 1;
    const int sch = (t & 1) * 2;
    const u16* ga = A + (size_t)(m0 + srow) * K + sch * 8;
    const u16* gb = Bt + (size_t)(n0 + srow) * K + sch * 8;
    const int wo = srow * LDT + sch * 8;

    u16x8 ra0 = *(const u16x8*)(ga);
    u16x8 ra1 = *(const u16x8*)(ga + 8);
    u16x8 rb0 = *(const u16x8*)(gb);
    u16x8 rb1 = *(const u16x8*)(gb + 8);
    *(u16x8*)&alds[0][wo] = ra0;  *(u16x8*)&alds[0][wo + 8] = ra1;
    *(u16x8*)&blds[0][wo] = rb0;  *(u16x8*)&blds[0][wo + 8] = rb1;

    f32x4 acc[4][4] = {};
    const int ko = (lane >> 4) * 8;
    const int arow_base = wm * 64 + (lane & 15);
    const int brow_base = wn * 64 + (lane & 15);

    int cur = 0;
    for (int kt = 0; kt < nk; ++kt) {
        __syncthreads();
        if (kt + 1 < nk) {
            const u16* gan = ga + (kt + 1) * 32;
            const u16* gbn = gb + (kt + 1) * 32;
            ra0 = *(const u16x8*)(gan);
            ra1 = *(const u16x8*)(gan + 8);
            rb0 = *(const u16x8*)(gbn);
            rb1 = *(const u16x8*)(gbn + 8);
        }
        bf16x8 afrag[4], bfrag[4];
#pragma unroll
        for (int m = 0; m < 4; ++m)
            afrag[m] = *(const bf16x8*)&alds[cur][(arow_base + m * 16) * LDT + ko];
#pragma unroll
        for (int n = 0; n < 4; ++n)
            bfrag[n] = *(const bf16x8*)&blds[cur][(brow_base + n * 16) * LDT + ko];
#pragma unroll
        for (int m = 0; m < 4; ++m)
#pragma unroll
            for (int n = 0; n < 4; ++n)
                acc[m][n] = __builtin_amdgcn_mfma_f32_16x16x32_bf16(afrag[m], bfrag[n],
                                                                   acc[m][n], 0, 0, 0);
        if (kt + 1 < nk) {
            *(u16x8*)&alds[cur ^ 1][wo] = ra0;  *(u16x8*)&alds[cur ^ 1][wo + 8] = ra1;
            *(u16x8*)&blds[cur ^ 1][wo] = rb0;  *(u16x8*)&blds[cur ^ 1][wo + 8] = rb1;
        }
        cur ^= 1;
    }

#pragma unroll
    for (int m = 0; m < 4; ++m)
#pragma unroll
        for (int n = 0; n < 4; ++n)
#pragma unroll
            for (int r = 0; r < 4; ++r) {
                int row = m0 + wm * 64 + m * 16 + (lane >> 4) * 4 + r;
                int col = n0 + wn * 64 + n * 16 + (lane & 15);
                size_t idx = (size_t)row * N + col;
                if (MODE == 0) Cb[idx] = f2bf(acc[m][n][r]);
                else           X[idx] = acc[m][n][r] + H[idx];
            }
}

// ---------------- V transpose ----------------
__global__ __launch_bounds__(256) void transpose_v_kernel(const u16* __restrict__ qkvb,
                                                          u16* __restrict__ vt) {
    __shared__ u16 tl[64][72];
    const int t = threadIdx.x;
    const int p = blockIdx.y;
    const int nn = p >> 1, b = p & 1;
    const int s0 = blockIdx.x * 64;
    const int r = t >> 2;
    const int ch = (t & 3) * 2;
    const u16* g = qkvb + ((size_t)(s0 + r) * 2 + b) * 3072 + 2048 + nn * 64;
    *(u16x8*)&tl[r][ch * 8]     = *(const u16x8*)(g + ch * 8);
    *(u16x8*)&tl[r][ch * 8 + 8] = *(const u16x8*)(g + ch * 8 + 8);
    __syncthreads();
    const int dh = t >> 2;
    const int sc = (t & 3) * 2;
    u16* o = vt + ((size_t)p * 64 + dh) * 2048 + s0;
#pragma unroll
    for (int q = 0; q < 2; ++q) {
        int scq = sc + q;
        u16x8 v;
#pragma unroll
        for (int j = 0; j < 8; ++j) v[j] = tl[scq * 8 + j][dh];
        *(u16x8*)(o + scq * 8) = v;
    }
}

// ---------------- causal flash attention (split-j, 8 waves) ----------------
// 2 wave-groups per block: group 0 = even j-tiles, group 1 = odd j-tiles, each with
// private double-buffered K/V LDS (r5-proven per-wave math: swapped QK^T in exp2
// units, permlane P-exchange, defer-rescale). Groups merge partials in LDS at end.
__global__ __launch_bounds__(512) void attn_kernel(const u16* __restrict__ qkvb,
                                                   const u16* __restrict__ vt,
                                                   u16* __restrict__ attnb) {
    constexpr int LKT = 72;               // 64 + 8 pad
    __shared__ u16 kvs[2][2][2][64 * LKT];   // [group][buf][K/V][row*LKT + col]
#if !USE_PERMLANE
    __shared__ u16 plds[8][16 * LKT];
#endif
    const int t = threadIdx.x;
    const int lane = t & 63;
    const int w = (t >> 6) & 3;           // wave within group
    const int grp = t >> 8;               // 0: even jt, 1: odd jt
    const int bid = blockIdx.x;
    const int qt = 31 - (bid >> 5);       // heavy q-tiles dispatched first
    const int p = bid & 31;
    const int nn = p >> 1, b = p & 1;
    const int i0 = qt * 64;

    const int li = lane & 15;
    const int lg = lane >> 4;

    // Q fragments (B-operand rows i = i0 + w*16 + li) — identical for both groups
    const int qrow = i0 + w * 16 + li;
    const u16* qg = qkvb + ((size_t)qrow * 2 + b) * 3072 + nn * 64 + lg * 8;
    bf16x8 qa0 = *(const bf16x8*)(qg);
    bf16x8 qa1 = *(const bf16x8*)(qg + 32);

    f32x4 o[4] = {};                      // O[row = lg*4+r][d = cf*16+li]
    float mrun = -3.0e38f;
    float lrun = 0.f;

    // staging geometry (group-local 256 threads)
    const int tg = t & 255;
    const int srow = tg >> 2;             // 0..63
    const int sch = (tg & 3) * 2;
    const u16* kg = qkvb + 1024 + nn * 64 + sch * 8;
    const u16* vg = vt + ((size_t)p * 64 + srow) * 2048 + sch * 8;
    const int swo = srow * LKT + sch * 8;

    const int nt = qt + 1;
    const int G = (nt + 1) >> 1;          // rounds per group

    u16x8 k0, k1, v0, v1;
    if (grp < nt) {                       // stage my first tile (jt = grp)
        const u16* kgp = kg + ((size_t)(grp * 64 + srow) * 2 + b) * 3072;
        k0 = *(const u16x8*)(kgp);  k1 = *(const u16x8*)(kgp + 8);
        const u16* vgp = vg + grp * 64;
        v0 = *(const u16x8*)(vgp);  v1 = *(const u16x8*)(vgp + 8);
        *(u16x8*)&kvs[grp][0][0][swo] = k0;  *(u16x8*)&kvs[grp][0][0][swo + 8] = k1;
        *(u16x8*)&kvs[grp][0][1][swo] = v0;  *(u16x8*)&kvs[grp][0][1][swo + 8] = v1;
    }
    __syncthreads();

    for (int s = 0; s < G; ++s) {
        const int jt = 2 * s + grp;
        const int buf = s & 1;
        const bool active = jt < nt;      // only group 1's last round can be inactive
        if (jt + 2 < nt) {                // issue-early my next tile
            const u16* kgp = kg + ((size_t)((jt + 2) * 64 + srow) * 2 + b) * 3072;
            k0 = *(const u16x8*)(kgp);  k1 = *(const u16x8*)(kgp + 8);
            const u16* vgp = vg + (jt + 2) * 64;
            v0 = *(const u16x8*)(vgp);  v1 = *(const u16x8*)(vgp + 8);
        }

        if (active) {
            const u16* kl = &kvs[grp][buf][0][0];
            const u16* vl = &kvs[grp][buf][1][0];

            // swapped QK^T: st[cf][r] = S^T[j = jt*64+cf*16+lg*4+r][i = i0+w*16+li]
            f32x4 st[4];
            __builtin_amdgcn_s_setprio(1);
#pragma unroll
            for (int cf = 0; cf < 4; ++cf) {
                bf16x8 kb0 = *(const bf16x8*)&kl[(cf * 16 + li) * LKT + lg * 8];
                bf16x8 kb1 = *(const bf16x8*)&kl[(cf * 16 + li) * LKT + 32 + lg * 8];
                f32x4 z = {};
                z = __builtin_amdgcn_mfma_f32_16x16x32_bf16(kb0, qa0, z, 0, 0, 0);
                z = __builtin_amdgcn_mfma_f32_16x16x32_bf16(kb1, qa1, z, 0, 0, 0);
                st[cf] = z;
            }
            __builtin_amdgcn_s_setprio(0);

            if (jt == qt) {               // mask only the diagonal tile
                const int it = w * 16 + li;
#pragma unroll
                for (int cf = 0; cf < 4; ++cf)
#pragma unroll
                    for (int r = 0; r < 4; ++r) {
                        int jl = cf * 16 + lg * 4 + r;
                        if (jl > it) st[cf][r] = -3.0e38f;
                    }
            }

            // row max: 15 in-reg + 2 shuffles
            float mloc = st[0][0];
#pragma unroll
            for (int cf = 0; cf < 4; ++cf)
#pragma unroll
                for (int r = 0; r < 4; ++r) mloc = fmaxf(mloc, st[cf][r]);
            mloc = fmaxf(mloc, __shfl_xor(mloc, 16, 64));
            mloc = fmaxf(mloc, __shfl_xor(mloc, 32, 64));

            // defer-rescale (T13)
            if (__any(mloc > mrun + 8.0f)) {
                float mnew = fmaxf(mrun, mloc);
                float alpha = fexp2(mrun - mnew);
                lrun *= alpha;
                mrun = mnew;
#pragma unroll
                for (int r = 0; r < 4; ++r) {
                    float ar = __shfl(alpha, lg * 4 + r, 64);
#pragma unroll
                    for (int cf = 0; cf < 4; ++cf) o[cf][r] *= ar;
                }
            }

#if USE_PERMLANE
            float rsum = 0.f;
            u32 wv[4][2];
#pragma unroll
            for (int cf = 0; cf < 4; ++cf)
#pragma unroll
                for (int rr = 0; rr < 2; ++rr) {
                    float p0 = fexp2(st[cf][2 * rr] - mrun);
                    float p1 = fexp2(st[cf][2 * rr + 1] - mrun);
                    rsum += p0 + p1;
                    u32 wres;
                    asm("v_cvt_pk_bf16_f32 %0, %1, %2" : "=v"(wres) : "v"(p0), "v"(p1));
                    wv[cf][rr] = wres;
                }
            rsum += __shfl_xor(rsum, 16, 64);
            rsum += __shfl_xor(rsum, 32, 64);
            lrun += rsum;

            __builtin_amdgcn_s_setprio(1);
#pragma unroll
            for (int ks = 0; ks < 2; ++ks) {
                u32x2 sa = __builtin_amdgcn_permlane32_swap(wv[2 * ks][0], wv[2 * ks + 1][0], false, false);
                u32x2 fa = __builtin_amdgcn_permlane16_swap(sa[0], sa[1], false, false);
                u32x2 sb = __builtin_amdgcn_permlane32_swap(wv[2 * ks][1], wv[2 * ks + 1][1], false, false);
                u32x2 fb = __builtin_amdgcn_permlane16_swap(sb[0], sb[1], false, false);
                u32x4 fw = { fa[0], fb[0], fa[1], fb[1] };
                bf16x8 pa = __builtin_bit_cast(bf16x8, fw);
#pragma unroll
                for (int cf = 0; cf < 4; ++cf) {
                    bf16x8 vb = *(const bf16x8*)&vl[(cf * 16 + li) * LKT + ks * 32 + lg * 8];
                    o[cf] = __builtin_amdgcn_mfma_f32_16x16x32_bf16(pa, vb, o[cf], 0, 0, 0);
                }
            }
            __builtin_amdgcn_s_setprio(0);
#else
            float rsum = 0.f;
#pragma unroll
            for (int cf = 0; cf < 4; ++cf) {
                u16x4 pw;
#pragma unroll
                for (int r = 0; r < 4; ++r) {
                    float pv = fexp2(st[cf][r] - mrun);
                    rsum += pv;
                    pw[r] = f2bf(pv);
                }
                *(u16x4*)&plds[t >> 6][li * LKT + cf * 16 + lg * 4] = pw;
            }
            rsum += __shfl_xor(rsum, 16, 64);
            rsum += __shfl_xor(rsum, 32, 64);
            lrun += rsum;

            asm volatile("s_waitcnt lgkmcnt(0)" ::: "memory");
            __builtin_amdgcn_sched_barrier(0);

#pragma unroll
            for (int ks = 0; ks < 2; ++ks) {
                bf16x8 pa = *(const bf16x8*)&plds[t >> 6][li * LKT + ks * 32 + lg * 8];
#pragma unroll
                for (int cf = 0; cf < 4; ++cf) {
                    bf16x8 vb = *(const bf16x8*)&vl[(cf * 16 + li) * LKT + ks * 32 + lg * 8];
                    o[cf] = __builtin_amdgcn_mfma_f32_16x16x32_bf16(pa, vb, o[cf], 0, 0, 0);
                }
            }
#endif
        }

        if (jt + 2 < nt) {                // write-late my next tile into other buffer
            *(u16x8*)&kvs[grp][buf ^ 1][0][swo] = k0;  *(u16x8*)&kvs[grp][buf ^ 1][0][swo + 8] = k1;
            *(u16x8*)&kvs[grp][buf ^ 1][1][swo] = v0;  *(u16x8*)&kvs[grp][buf ^ 1][1][swo + 8] = v1;
        }
        __syncthreads();
    }

    // ---- merge group partials (online-softmax combine) ----
    // group 1 spills (o, m, l) into its K/V LDS region; group 0 merges + stores.
    float* osc = (float*)&kvs[1][0][0][0];       // [64 rows][65] f32
    float* msc = osc + 64 * 65;                  // [64]
    float* lsc = msc + 64;                       // [64]
    if (grp == 1) {
#pragma unroll
        for (int cf = 0; cf < 4; ++cf)
#pragma unroll
            for (int r = 0; r < 4; ++r)
                osc[(w * 16 + lg * 4 + r) * 65 + cf * 16 + li] = o[cf][r];
        if (lg == 0) { msc[w * 16 + li] = mrun; lsc[w * 16 + li] = lrun; }
    }
    __syncthreads();
    if (grp == 0) {
        float mB = msc[w * 16 + li];
        float lB = lsc[w * 16 + li];
        float m = fmaxf(mrun, mB);
        float eA = fexp2(mrun - m);
        float eB = fexp2(mB - m);
        float linv = frcp(lrun * eA + lB * eB);
#pragma unroll
        for (int r = 0; r < 4; ++r) {
            float eAr = __shfl(eA, lg * 4 + r, 64);
            float eBr = __shfl(eB, lg * 4 + r, 64);
            float rvr = __shfl(linv, lg * 4 + r, 64);
            int row = i0 + w * 16 + lg * 4 + r;
            u16* og = attnb + ((size_t)row * 2 + b) * 1024 + nn * 64;
#pragma unroll
            for (int cf = 0; cf < 4; ++cf) {
                float ob = osc[(w * 16 + lg * 4 + r) * 65 + cf * 16 + li];
                og[cf * 16 + li] = f2bf((o[cf][r] * eAr + ob * eBr) * rvr);
            }
        }
    }
}

// ---------------- residual LayerNorm ----------------
__global__ __launch_bounds__(256) void ln_kernel(const float* __restrict__ X,
                                                 const float* __restrict__ gamma,
                                                 const float* __restrict__ beta,
                                                 float* __restrict__ out) {
    __shared__ float red[8];
    const int t = threadIdx.x;
    const int row = blockIdx.x;
    float4 v = ((const float4*)(X + (size_t)row * 1024))[t];
    float s = v.x + v.y + v.z + v.w;
#pragma unroll
    for (int off = 1; off < 64; off <<= 1) s += __shfl_xor(s, off, 64);
    if ((t & 63) == 0) red[t >> 6] = s;
    __syncthreads();
    float mu = (red[0] + red[1] + red[2] + red[3]) * (1.f / 1024.f);
    float dx = v.x - mu, dy = v.y - mu, dz = v.z - mu, dw = v.w - mu;
    float q = dx * dx + dy * dy + dz * dz + dw * dw;
#pragma unroll
    for (int off = 1; off < 64; off <<= 1) q += __shfl_xor(q, off, 64);
    if ((t & 63) == 0) red[4 + (t >> 6)] = q;
    __syncthreads();
    float var = (red[4] + red[5] + red[6] + red[7]) * (1.f / 1024.f);
    float rs = rsqrtf(var + 1e-5f);
    float4 g = ((const float4*)gamma)[t];
    float4 bt = ((const float4*)beta)[t];
    float4 o;
    o.x = dx * rs * g.x + bt.x;
    o.y = dy * rs * g.y + bt.y;
    o.z = dz * rs * g.z + bt.z;
    o.w = dw * rs * g.w + bt.w;
    ((float4*)(out + (size_t)row * 1024))[t] = o;
}

// ---------------- launch ----------------
extern "C" void kernel_launch(void* const* d_in, const int* in_sizes, int n_in,
                              void* d_out, int out_size, void* d_ws, size_t ws_size,
                              hipStream_t stream) {
    const float* h     = (const float*)d_in[0];
    // d_in[1] = attn_mask (deterministic causal triu; applied analytically)
    const float* Wqkv  = (const float*)d_in[2];
    const float* Wo    = (const float*)d_in[3];
    const float* gamma = (const float*)d_in[4];
    const float* beta  = (const float*)d_in[5];
    float* out = (float*)d_out;

    char* ws = (char*)d_ws;
    u16*   hb    = (u16*)(ws);
    u16*   wqkvt = (u16*)(ws + 8388608);
    u16*   wot   = (u16*)(ws + 14680064);
    u16*   qkvb  = (u16*)(ws + 16777216);
    u16*   vt    = (u16*)(ws + 41943040);
    u16*   attnb = (u16*)(ws + 50331648);
    float* xbuf  = (float*)(ws + 58720256);

    const float qscale = 0.125f * 1.44269504088896f;  // 1/sqrt(Dh) * log2(e)

    conv_h_kernel<<<4096, 256, 0, stream>>>(h, hb);
    conv_wt_kernel<<<dim3(96, 32), 256, 0, stream>>>(Wqkv, wqkvt, 1024, 3072, 1024, qscale);
    conv_wt_kernel<<<dim3(32, 32), 256, 0, stream>>>(Wo, wot, 1024, 1024, 0, 1.0f);
    gemm_bt_kernel<0><<<dim3(32, 24), 256, 0, stream>>>(hb, wqkvt, qkvb, nullptr, nullptr,
                                                        4096, 3072, 1024);
    transpose_v_kernel<<<dim3(32, 32), 256, 0, stream>>>(qkvb, vt);
    attn_kernel<<<1024, 512, 0, stream>>>(qkvb, vt, attnb);
    gemm_bt_kernel<1><<<dim3(32, 8), 256, 0, stream>>>(attnb, wot, nullptr, h, xbuf,
                                                       4096, 1024, 1024);
    ln_kernel<<<4096, 256, 0, stream>>>(xbuf, gamma, beta, out);
}